// Round 5
// baseline (672.973 us; speedup 1.0000x reference)
//
#include <hip/hip_runtime.h>
#include <math.h>

#define NT 256

typedef __attribute__((ext_vector_type(8))) short s16x8;
typedef __attribute__((ext_vector_type(4))) float f32x4;

// d_ws layout (bytes)
#define KVF_OFF 0        // bf16 KV B-frags: [h][nt3][kk4][512]   -> 73728 B
#define QF_OFF  73728    // bf16 q  B-frags: [h][nt2][kk4][512]   -> 49152 B
#define PJF_OFF 122880   // bf16 proj A-frags: [h][ct8][512] K=32 -> 49152 B
#define RPB_OFF 172032   // fp32 rpb^T: [h][tok192][q64]          -> 294912 B

__device__ __forceinline__ unsigned short f2bf(float f) {
    union { float f; unsigned int i; } v; v.f = f;
    unsigned int x = v.i;
    x += 0x7fffu + ((x >> 16) & 1u);   // round-nearest-even
    return (unsigned short)(x >> 16);
}
// packed fp32->bf16 (RNE) — bit-manip version (proven in rounds 0-1; asm cvt_pk NaN'd in r4)
__device__ __forceinline__ unsigned int pk2(float a, float b) {
    return (unsigned int)f2bf(a) | ((unsigned int)f2bf(b) << 16);
}
__device__ __forceinline__ s16x8 cvt8(float4 a, float4 b) {
    union { unsigned int u[4]; s16x8 v; } r;
    r.u[0] = pk2(a.x, a.y);
    r.u[1] = pk2(a.z, a.w);
    r.u[2] = pk2(b.x, b.y);
    r.u[3] = pk2(b.z, b.w);
    return r.v;
}

#define MFMA(a, b, c) __builtin_amdgcn_mfma_f32_16x16x32_bf16(a, b, c, 0, 0, 0)

// ---------------- prep: weights -> bf16 fragments, rpb gathered+transposed ----------------
__global__ void prep(const float* __restrict__ qkv_w,
                     const float* __restrict__ proj_w,
                     const float* __restrict__ rpb_table,
                     const int*   __restrict__ rel_idx,
                     unsigned char* __restrict__ wsb)
{
    int gid = blockIdx.x * blockDim.x + threadIdx.x;
    int nthr = gridDim.x * blockDim.x;
    unsigned short* KVF = (unsigned short*)(wsb + KVF_OFF);
    unsigned short* QF  = (unsigned short*)(wsb + QF_OFF);
    unsigned short* PJF = (unsigned short*)(wsb + PJF_OFF);
    float*          RPB = (float*)(wsb + RPB_OFF);

    // KV fragments: f = ((h*3+nt)*4+kk)*512 + ln*8 + j
    for (int f = gid; f < 6 * 3 * 4 * 512; f += nthr) {
        int q = f & 511, rest = f >> 9;
        int kk = rest & 3, rest2 = rest >> 2;
        int nt = rest2 % 3, h = rest2 / 3;
        int ln = q >> 3, j = q & 7;
        int l15 = ln & 15, qd = ln >> 4;
        int nglob = nt * 16 + l15, k = kk * 32 + qd * 8 + j;
        float v = 0.f;
        if (k < 120 && nglob < 40) {
            int row = (nglob < 20) ? (120 + h * 20 + nglob) : (240 + h * 20 + nglob - 20);
            v = qkv_w[row * 120 + k];
        }
        KVF[f] = f2bf(v);
    }
    // q fragments: f = ((h*2+nt)*4+kk)*512 + ln*8 + j
    for (int f = gid; f < 6 * 2 * 4 * 512; f += nthr) {
        int q = f & 511, rest = f >> 9;
        int kk = rest & 3, rest2 = rest >> 2;
        int nt = rest2 & 1, h = rest2 >> 1;
        int ln = q >> 3, j = q & 7;
        int l15 = ln & 15, qd = ln >> 4;
        int nn = nt * 16 + l15, k = kk * 32 + qd * 8 + j;
        int row = h * 20 + nn;                    // <=131, always valid memory
        float v = (k < 120) ? qkv_w[row * 120 + k] : 0.f;
        QF[f] = f2bf(v);
    }
    // proj fragments, per-head K=32 slice: f = ((h*8+ct))*512 + ln*8 + j
    for (int f = gid; f < 6 * 8 * 512; f += nthr) {
        int q = f & 511, rest = f >> 9;
        int ct = rest & 7, h = rest >> 3;
        int ln = q >> 3, j = q & 7;
        int l15 = ln & 15, qd = ln >> 4;
        int c = ct * 16 + l15, k = qd * 8 + j;
        float v = (k < 20 && c < 120) ? proj_w[c * 120 + h * 20 + k] : 0.f;
        PJF[f] = f2bf(v);
    }
    // rpb transposed: [h][tok(192)][q(64)] fp32
    for (int i = gid; i < 6 * 192 * 64; i += nthr) {
        int r = i & 63, n = (i >> 6) % 192, h = i / (192 * 64);
        RPB[i] = rpb_table[rel_idx[r * 192 + n] * 6 + h];
    }
}

// ---------------- main fused kernel: round-1 structure, no xw LDS, 4 blocks/CU ----------------
__global__ __launch_bounds__(NT, 4)
void swin_mfma(const float* __restrict__ x,
               const float* __restrict__ quary0,
               const float* __restrict__ quary1,
               const float* __restrict__ qkv_b,
               const float* __restrict__ proj_b,
               const float* __restrict__ pm_w,
               const float* __restrict__ pm_b,
               const unsigned char* __restrict__ wsb,
               float* __restrict__ out)
{
    // 33,792 B total -> 4 blocks/CU (16 waves/CU, 4/SIMD)
    __shared__ alignas(16) unsigned char smem[33792];
    unsigned short* ks = (unsigned short*)smem;             // k:[192][40], cols 20..31 zero (15360 B)
    unsigned short* vt = (unsigned short*)(smem + 15360);   // v^T:[32][200], rows 20..31 zero (12800 B)
    unsigned short* qs = (unsigned short*)(smem + 28160);   // q:[64][40], cols 20..31 zero  (5120 B)
    float* pred_s = (float*)(smem + 33280);                 // 64 floats
    int*   grp_s  = (int*)(smem + 33536);                   // 64 ints

    const int tid = threadIdx.x;
    const int wv = tid >> 6, ln = tid & 63;
    const int l15 = ln & 15, qd = ln >> 4;
    const int widx = blockIdx.x;
    const int wh = widx >> 5, ww = widx & 31;
    const float SCALE = 0.22360679774997896f;   // 20^-0.5

    const unsigned short* KVF = (const unsigned short*)(wsb + KVF_OFF);
    const unsigned short* QF  = (const unsigned short*)(wsb + QF_OFF);
    const unsigned short* PJF = (const unsigned short*)(wsb + PJF_OFF);
    const float*          RPB = (const float*)(wsb + RPB_OFF);

    // ---------------- prologue: zero pads, region ids, pred ----------------
    for (int e = tid; e < 192 * 12; e += NT) ks[(e / 12) * 40 + 20 + (e % 12)] = 0;
    for (int e = tid; e < 64 * 12;  e += NT) qs[(e / 12) * 40 + 20 + (e % 12)] = 0;
    for (int e = tid; e < 12 * 200; e += NT) vt[(20 + e / 200) * 200 + (e % 200)] = 0;
    if (tid < 64) {                                          // shift-mask region ids
        int ii = tid >> 3, jj = tid & 7;
        int y0 = (wh * 8 + ii + 4) & 255;
        int x0 = (ww * 8 + jj + 4) & 255;
        int hg = (y0 >= 248) + (y0 >= 252);
        int wg = (x0 >= 248) + (x0 >= 252);
        grp_s[tid] = hg * 3 + wg;
    }
    {                                                        // pred in exact fp32
        int r = tid >> 2, j = tid & 3;
        int ii = r >> 3, jj = r & 7;
        int y0 = (wh * 8 + ii + 4) & 255;
        int x0 = (ww * 8 + jj + 4) & 255;
        const float* xr  = x + (((size_t)(2 * 256 + y0)) * 256 + x0) * 120;
        const float* q0r = quary0 + ((size_t)widx * 64 + r) * 120;
        float acc = 0.f;
        for (int ch = j * 30; ch < j * 30 + 30; ++ch)
            acc += fabsf(xr[ch] - q0r[ch]) * pm_w[ch];
        acc += __shfl_xor(acc, 1);
        acc += __shfl_xor(acc, 2);
        if (j == 0) pred_s[r] = (acc + pm_b[0] >= 0.f) ? 1.f : 0.f;
    }
    __syncthreads();

    // ---------------- per-lane constants for the swapped-attention path ----------------
    const int q_l = wv * 16 + l15;               // this wave's q row (0..63)
    const int gq = grp_s[q_l];
    unsigned long long mbits = 0ull;             // bit(t*4+r) = mask(-100) for tok=t*16+qd*4+r
    #pragma unroll
    for (int t = 0; t < 12; ++t)
        #pragma unroll
        for (int r = 0; r < 4; ++r) {
            int tok = t * 16 + qd * 4 + r;
            if (gq != grp_s[tok & 63]) mbits |= (1ull << (t * 4 + r));
        }
    // shuffle sources for P^T/O^T -> B-frag redistribution
    const int srcA = (((qd * 2) & 3) << 4) | l15;
    const int srcB = (((qd * 2 + 1) & 3) << 4) | l15;
    const int msel = qd >> 1;                    // selects which shuffled word pair

    f32x4 pacc[8];                               // proj accumulators x1^T[c-tile][q=l15]
    #pragma unroll
    for (int i = 0; i < 8; ++i) { f32x4 z = {0.f,0.f,0.f,0.f}; pacc[i] = z; }

    // ---------------- head loop ----------------
    for (int h = 0; h < 6; ++h) {
        // ---- phase 1: QKV GEMMs for head h; A-frags straight from global x ----
        for (int e = wv; e < 44; e += 4) {
            if (e < 36) {
                int mt = e % 12, nt = e / 12;
                int n = mt * 16 + l15;
                int f = n >> 6, ii = (n >> 3) & 7, jj = n & 7;
                int y0 = (wh * 8 + ii + 4) & 255;
                int x0 = (ww * 8 + jj + 4) & 255;
                const float* xr = x + (((size_t)(f * 256 + y0)) * 256 + x0) * 120;
                const unsigned short* bbase = KVF + ((h * 3 + nt) * 4) * 512 + ln * 8;
                f32x4 acc = {0.f, 0.f, 0.f, 0.f};
                #pragma unroll
                for (int kk = 0; kk < 4; ++kk) {
                    float4 va = {0.f,0.f,0.f,0.f}, vb = {0.f,0.f,0.f,0.f};
                    if (!(kk == 3 && qd == 3)) { // ch 120..127: killed by zero B-frags; avoid OOB
                        va = *(const float4*)(xr + kk * 32 + qd * 8);
                        vb = *(const float4*)(xr + kk * 32 + qd * 8 + 4);
                    }
                    acc = MFMA(cvt8(va, vb), *(const s16x8*)(bbase + kk * 512), acc);
                }
                int nglob = nt * 16 + l15;
                if (nglob < 40) {
                    float bias = qkv_b[nglob < 20 ? (120 + h * 20 + nglob)
                                                  : (240 + h * 20 + nglob - 20)];
                    #pragma unroll
                    for (int reg = 0; reg < 4; ++reg) {
                        int tok = mt * 16 + qd * 4 + reg;
                        unsigned short vbf = f2bf(acc[reg] + bias);
                        if (nglob < 20) ks[tok * 40 + nglob] = vbf;
                        else            vt[(nglob - 20) * 200 + tok] = vbf;
                    }
                }
            } else {
                int t = e - 36, mt = t & 3, nt = t >> 2;
                int n = 128 + mt * 16 + l15;
                int f = n >> 6, ii = (n >> 3) & 7, jj = n & 7;
                int y0 = (wh * 8 + ii + 4) & 255;
                int x0 = (ww * 8 + jj + 4) & 255;
                const float* xr = x + (((size_t)(f * 256 + y0)) * 256 + x0) * 120;
                const unsigned short* bbase = QF + ((h * 2 + nt) * 4) * 512 + ln * 8;
                f32x4 acc = {0.f, 0.f, 0.f, 0.f};
                #pragma unroll
                for (int kk = 0; kk < 4; ++kk) {
                    float4 va = {0.f,0.f,0.f,0.f}, vb = {0.f,0.f,0.f,0.f};
                    if (!(kk == 3 && qd == 3)) {
                        va = *(const float4*)(xr + kk * 32 + qd * 8);
                        vb = *(const float4*)(xr + kk * 32 + qd * 8 + 4);
                    }
                    acc = MFMA(cvt8(va, vb), *(const s16x8*)(bbase + kk * 512), acc);
                }
                int nn = nt * 16 + l15;
                if (nn < 20) {
                    float bias = qkv_b[h * 20 + nn];
                    #pragma unroll
                    for (int reg = 0; reg < 4; ++reg)
                        qs[(mt * 16 + qd * 4 + reg) * 40 + nn] = f2bf((acc[reg] + bias) * SCALE);
                }
            }
        }
        __syncthreads();

        // ---- phase 2: swapped scores S^T = K·Q^T, in-register softmax/PV/proj ----
        const float* rbase = RPB + ((size_t)(h * 192 + qd * 4)) * 64 + q_l;
        float vals[48];
        #pragma unroll
        for (int t = 0; t < 12; ++t)
            #pragma unroll
            for (int r = 0; r < 4; ++r)
                vals[t * 4 + r] = rbase[(t * 16 + r) * 64]
                                + (((mbits >> (t * 4 + r)) & 1ull) ? -100.f : 0.f);

        const s16x8 bQ = *(const s16x8*)(qs + q_l * 40 + qd * 8);
        f32x4 sc[12];
        #pragma unroll
        for (int t = 0; t < 12; ++t) {
            s16x8 aK = *(const s16x8*)(ks + (t * 16 + l15) * 40 + qd * 8);
            f32x4 z = {0.f, 0.f, 0.f, 0.f};
            sc[t] = MFMA(aK, bQ, z);             // S^T[tok=t*16+qd*4+reg][q=q_l]
        }

        float m = -1e30f;
        #pragma unroll
        for (int t = 0; t < 12; ++t)
            #pragma unroll
            for (int r = 0; r < 4; ++r) {
                float v = vals[t * 4 + r] + sc[t][r];
                vals[t * 4 + r] = v; m = fmaxf(m, v);
            }
        m = fmaxf(m, __shfl_xor(m, 16));
        m = fmaxf(m, __shfl_xor(m, 32));
        float s = 0.f;
        #pragma unroll
        for (int i = 0; i < 48; ++i) { float ev = __expf(vals[i] - m); vals[i] = ev; s += ev; }
        s += __shfl_xor(s, 16);
        s += __shfl_xor(s, 32);
        float inv = 1.0f / s;

        unsigned int plo[12], phi[12];           // P^T packed: regs(0,1) / regs(2,3) per tok-tile
        #pragma unroll
        for (int t = 0; t < 12; ++t) {
            plo[t] = pk2(vals[t * 4 + 0] * inv, vals[t * 4 + 1] * inv);
            phi[t] = pk2(vals[t * 4 + 2] * inv, vals[t * 4 + 3] * inv);
        }

        // PV: O^T = V^T · P^T   (A = vt rows, B built by cross-lane redistribution)
        f32x4 o0 = {0.f,0.f,0.f,0.f}, o1 = {0.f,0.f,0.f,0.f};
        #pragma unroll
        for (int kk = 0; kk < 6; ++kk) {
            unsigned int a0 = __shfl(plo[2 * kk],     srcA);
            unsigned int a1 = __shfl(plo[2 * kk + 1], srcA);
            unsigned int b0 = __shfl(phi[2 * kk],     srcA);
            unsigned int b1 = __shfl(phi[2 * kk + 1], srcA);
            unsigned int c0 = __shfl(plo[2 * kk],     srcB);
            unsigned int c1 = __shfl(plo[2 * kk + 1], srcB);
            unsigned int d0 = __shfl(phi[2 * kk],     srcB);
            unsigned int d1 = __shfl(phi[2 * kk + 1], srcB);
            union { s16x8 v; unsigned int u[4]; } bf;
            bf.u[0] = msel ? a1 : a0;
            bf.u[1] = msel ? b1 : b0;
            bf.u[2] = msel ? c1 : c0;
            bf.u[3] = msel ? d1 : d0;
            s16x8 aV0 = *(const s16x8*)(vt + l15 * 200 + kk * 32 + qd * 8);
            s16x8 aV1 = *(const s16x8*)(vt + (16 + l15) * 200 + kk * 32 + qd * 8);
            o0 = MFMA(aV0, bf.v, o0);            // O^T[d=qd*4+reg][q]
            o1 = MFMA(aV1, bf.v, o1);            // O^T[d=16+qd*4+reg][q]
        }

        // proj: x1^T += PW_h · O^T_h  (B-frag from O^T via same redistribution)
        {
            unsigned int ol0 = pk2(o0[0], o0[1]), oh0 = pk2(o0[2], o0[3]);
            unsigned int ol1 = pk2(o1[0], o1[1]), oh1 = pk2(o1[2], o1[3]);
            unsigned int w0a = __shfl(ol0, srcA), w0b = __shfl(ol1, srcA);
            unsigned int w1a = __shfl(oh0, srcA), w1b = __shfl(oh1, srcA);
            unsigned int w2a = __shfl(ol0, srcB), w2b = __shfl(ol1, srcB);
            unsigned int w3a = __shfl(oh0, srcB), w3b = __shfl(oh1, srcB);
            union { s16x8 v; unsigned int u[4]; } bo;
            bo.u[0] = msel ? w0b : w0a;
            bo.u[1] = msel ? w1b : w1a;
            bo.u[2] = msel ? w2b : w2a;
            bo.u[3] = msel ? w3b : w3a;
            #pragma unroll
            for (int ct = 0; ct < 8; ++ct) {
                s16x8 aP = *(const s16x8*)(PJF + (h * 8 + ct) * 512 + ln * 8);
                pacc[ct] = MFMA(aP, bo.v, pacc[ct]);
            }
        }
        __syncthreads();
    }

    // ---------------- epilogue: transpose via LDS overlay, blend, scatter ----------------
    float* xo = (float*)smem;                    // [64][129] fp32 overlay on dead ks/vt/qs (33,024 B)
    #pragma unroll
    for (int ct = 0; ct < 8; ++ct)
        #pragma unroll
        for (int r = 0; r < 4; ++r) {
            int c = ct * 16 + qd * 4 + r;
            if (c < 120) xo[q_l * 129 + c] = pacc[ct][r];
        }
    __syncthreads();

    for (int e = tid; e < 64 * 121; e += NT) {
        int r = e / 121, c = e - r * 121;
        int ii = r >> 3, jj = r & 7;
        int y0 = (wh * 8 + ii + 4) & 255;
        int x0 = (ww * 8 + jj + 4) & 255;
        float p = pred_s[r];
        float val;
        if (c < 120)
            val = (p != 0.f) ? (xo[r * 129 + c] + proj_b[c])
                             : quary1[(size_t)widx * 7680 + (size_t)r * 120 + c];
        else
            val = p;
        out[((size_t)(y0 * 256 + x0)) * 121 + c] = val;
    }
}

extern "C" void kernel_launch(void* const* d_in, const int* in_sizes, int n_in,
                              void* d_out, int out_size, void* d_ws, size_t ws_size,
                              hipStream_t stream) {
    const float* x        = (const float*)d_in[0];
    const float* quary0   = (const float*)d_in[1];
    const float* quary1   = (const float*)d_in[2];
    const float* qkv_w    = (const float*)d_in[3];
    const float* qkv_b    = (const float*)d_in[4];
    const float* proj_w   = (const float*)d_in[5];
    const float* proj_b   = (const float*)d_in[6];
    const float* rpb      = (const float*)d_in[7];
    const float* pm_w     = (const float*)d_in[8];
    const float* pm_b     = (const float*)d_in[9];
    const int*   rel_idx  = (const int*)d_in[11];
    float* out = (float*)d_out;
    unsigned char* wsb = (unsigned char*)d_ws;

    prep<<<128, 512, 0, stream>>>(qkv_w, proj_w, rpb, rel_idx, wsb);
    swin_mfma<<<1024, NT, 0, stream>>>(x, quary0, quary1, qkv_b, proj_b,
                                       pm_w, pm_b, wsb, out);
}

// Round 6
// 435.960 us; speedup vs baseline: 1.5437x; 1.5437x over previous
//
#include <hip/hip_runtime.h>
#include <math.h>

#define NT 256

typedef __attribute__((ext_vector_type(8))) short s16x8;
typedef __attribute__((ext_vector_type(4))) float f32x4;

// d_ws layout (bytes)
#define KVF_OFF 0        // bf16 KV B-frags: [h][nt3][kk4][512]   -> 73728 B
#define QF_OFF  73728    // bf16 q  B-frags: [h][nt2][kk4][512]   -> 49152 B
#define PJF_OFF 122880   // bf16 proj A-frags: [h][ct8][512] K=32 -> 49152 B
#define RPB_OFF 172032   // fp32 rpb^T: [h][tok192][q64]          -> 294912 B

__device__ __forceinline__ unsigned short f2bf(float f) {
    union { float f; unsigned int i; } v; v.f = f;
    unsigned int x = v.i;
    x += 0x7fffu + ((x >> 16) & 1u);   // round-nearest-even
    return (unsigned short)(x >> 16);
}
__device__ __forceinline__ unsigned int pk2(float a, float b) {
    return (unsigned int)f2bf(a) | ((unsigned int)f2bf(b) << 16);
}

#define MFMA(a, b, c) __builtin_amdgcn_mfma_f32_16x16x32_bf16(a, b, c, 0, 0, 0)

// ---------------- prep: weights -> bf16 fragments, rpb gathered+transposed ----------------
__global__ void prep(const float* __restrict__ qkv_w,
                     const float* __restrict__ proj_w,
                     const float* __restrict__ rpb_table,
                     const int*   __restrict__ rel_idx,
                     unsigned char* __restrict__ wsb)
{
    int gid = blockIdx.x * blockDim.x + threadIdx.x;
    int nthr = gridDim.x * blockDim.x;
    unsigned short* KVF = (unsigned short*)(wsb + KVF_OFF);
    unsigned short* QF  = (unsigned short*)(wsb + QF_OFF);
    unsigned short* PJF = (unsigned short*)(wsb + PJF_OFF);
    float*          RPB = (float*)(wsb + RPB_OFF);

    // KV fragments: f = ((h*3+nt)*4+kk)*512 + ln*8 + j
    for (int f = gid; f < 6 * 3 * 4 * 512; f += nthr) {
        int q = f & 511, rest = f >> 9;
        int kk = rest & 3, rest2 = rest >> 2;
        int nt = rest2 % 3, h = rest2 / 3;
        int ln = q >> 3, j = q & 7;
        int l15 = ln & 15, qd = ln >> 4;
        int nglob = nt * 16 + l15, k = kk * 32 + qd * 8 + j;
        float v = 0.f;
        if (k < 120 && nglob < 40) {
            int row = (nglob < 20) ? (120 + h * 20 + nglob) : (240 + h * 20 + nglob - 20);
            v = qkv_w[row * 120 + k];
        }
        KVF[f] = f2bf(v);
    }
    // q fragments: f = ((h*2+nt)*4+kk)*512 + ln*8 + j
    for (int f = gid; f < 6 * 2 * 4 * 512; f += nthr) {
        int q = f & 511, rest = f >> 9;
        int kk = rest & 3, rest2 = rest >> 2;
        int nt = rest2 & 1, h = rest2 >> 1;
        int ln = q >> 3, j = q & 7;
        int l15 = ln & 15, qd = ln >> 4;
        int nn = nt * 16 + l15, k = kk * 32 + qd * 8 + j;
        int row = h * 20 + nn;                    // <=131, always valid memory
        float v = (k < 120) ? qkv_w[row * 120 + k] : 0.f;
        QF[f] = f2bf(v);
    }
    // proj fragments, per-head K=32 slice: f = ((h*8+ct))*512 + ln*8 + j
    for (int f = gid; f < 6 * 8 * 512; f += nthr) {
        int q = f & 511, rest = f >> 9;
        int ct = rest & 7, h = rest >> 3;
        int ln = q >> 3, j = q & 7;
        int l15 = ln & 15, qd = ln >> 4;
        int c = ct * 16 + l15, k = qd * 8 + j;
        float v = (k < 20 && c < 120) ? proj_w[c * 120 + h * 20 + k] : 0.f;
        PJF[f] = f2bf(v);
    }
    // rpb transposed: [h][tok(192)][q(64)] fp32
    for (int i = gid; i < 6 * 192 * 64; i += nthr) {
        int r = i & 63, n = (i >> 6) % 192, h = i / (192 * 64);
        RPB[i] = rpb_table[rel_idx[r * 192 + n] * 6 + h];
    }
}

// ---------------- main fused kernel: r1 structure + head-pipelined epochs ----------------
// LDS: xw@0 (46096) | ks@46096 [192][24] (9216) | qs@55312 [2][64][24] (6144)
//      vt@61456 [2][20][200] (16000) | pred@77456 (256) | grp@77712 (256)  = 77968 B
__global__ __launch_bounds__(NT, 2)
void swin_mfma(const float* __restrict__ x,
               const float* __restrict__ quary0,
               const float* __restrict__ quary1,
               const float* __restrict__ qkv_b,
               const float* __restrict__ proj_b,
               const float* __restrict__ pm_w,
               const float* __restrict__ pm_b,
               const unsigned char* __restrict__ wsb,
               float* __restrict__ out)
{
    __shared__ alignas(16) unsigned char smem[77968];
    unsigned short* xw = (unsigned short*)smem;             // [192][120] + 8 pad
    unsigned short* ks = (unsigned short*)(smem + 46096);   // K [192][24], cols 20..23 zero
    unsigned short* qs = (unsigned short*)(smem + 55312);   // Q [2][64][24], cols 20..23 zero
    unsigned short* vt = (unsigned short*)(smem + 61456);   // V^T [2][20][200]
    float* pred_s = (float*)(smem + 77456);                 // 64 floats
    int*   grp_s  = (int*)(smem + 77712);                   // 64 ints

    const int tid = threadIdx.x;
    const int wv = tid >> 6, ln = tid & 63;
    const int l15 = ln & 15, qd = ln >> 4;
    const int widx = blockIdx.x;
    const int wh = widx >> 5, ww = widx & 31;
    const float SCALE = 0.22360679774997896f;   // 20^-0.5

    const unsigned short* KVF = (const unsigned short*)(wsb + KVF_OFF);
    const unsigned short* QF  = (const unsigned short*)(wsb + QF_OFF);
    const unsigned short* PJF = (const unsigned short*)(wsb + PJF_OFF);
    const float*          RPB = (const float*)(wsb + RPB_OFF);

    // ---------------- staging / prologue ----------------
    for (int e = tid; e < 192 * 30; e += NT) {
        int n = e / 30, c4 = e % 30;
        int f = n >> 6, ii = (n >> 3) & 7, jj = n & 7;
        int y0 = (wh * 8 + ii + 4) & 255;
        int x0 = (ww * 8 + jj + 4) & 255;
        float4 val = *(const float4*)(x + (((size_t)(f * 256 + y0)) * 256 + x0) * 120 + c4 * 4);
        unsigned int lo = pk2(val.x, val.y);
        unsigned int hi = pk2(val.z, val.w);
        unsigned int off = (unsigned)(n * 120 + c4 * 4);
        *(unsigned int*)(xw + off)     = lo;
        *(unsigned int*)(xw + off + 2) = hi;
    }
    if (tid < 8) xw[192 * 120 + tid] = 0;
    for (int e = tid; e < 192 * 4; e += NT) ks[(e >> 2) * 24 + 20 + (e & 3)] = 0;
    for (int e = tid; e < 2 * 64 * 4; e += NT)
        qs[(e >> 8) * 1536 + ((e >> 2) & 63) * 24 + 20 + (e & 3)] = 0;
    if (tid < 64) {                                          // shift-mask region ids
        int ii = tid >> 3, jj = tid & 7;
        int y0 = (wh * 8 + ii + 4) & 255;
        int x0 = (ww * 8 + jj + 4) & 255;
        int hg = (y0 >= 248) + (y0 >= 252);
        int wg = (x0 >= 248) + (x0 >= 252);
        grp_s[tid] = hg * 3 + wg;
    }
    {                                                        // pred in exact fp32
        int r = tid >> 2, j = tid & 3;
        int ii = r >> 3, jj = r & 7;
        int y0 = (wh * 8 + ii + 4) & 255;
        int x0 = (ww * 8 + jj + 4) & 255;
        const float* xr  = x + (((size_t)(2 * 256 + y0)) * 256 + x0) * 120;
        const float* q0r = quary0 + ((size_t)widx * 64 + r) * 120;
        float acc = 0.f;
        for (int ch = j * 30; ch < j * 30 + 30; ++ch)
            acc += fabsf(xr[ch] - q0r[ch]) * pm_w[ch];
        acc += __shfl_xor(acc, 1);
        acc += __shfl_xor(acc, 2);
        if (j == 0) pred_s[r] = (acc + pm_b[0] >= 0.f) ? 1.f : 0.f;
    }
    __syncthreads();

    // ---------------- job helpers ----------------
    auto kvjob = [&](int mt, int nt, int hh, int pty) {
        const unsigned short* arow  = xw + (mt * 16 + l15) * 120;
        const unsigned short* bbase = KVF + ((hh * 3 + nt) * 4) * 512 + ln * 8;
        f32x4 acc = {0.f, 0.f, 0.f, 0.f};
        #pragma unroll
        for (int kk = 0; kk < 4; ++kk)
            acc = MFMA(*(const s16x8*)(arow + kk * 32 + qd * 8),
                       *(const s16x8*)(bbase + kk * 512), acc);
        int nglob = nt * 16 + l15;
        if (nglob < 40) {
            float bias = qkv_b[nglob < 20 ? (120 + hh * 20 + nglob)
                                          : (240 + hh * 20 + nglob - 20)];
            #pragma unroll
            for (int reg = 0; reg < 4; ++reg) {
                int tok = mt * 16 + qd * 4 + reg;
                unsigned short vb = f2bf(acc[reg] + bias);
                if (nglob < 20) ks[tok * 24 + nglob] = vb;
                else            vt[pty * 4000 + (nglob - 20) * 200 + tok] = vb;
            }
        }
    };
    auto qjob = [&](int mt, int nt, int hh, int pty) {
        const unsigned short* arow  = xw + (128 + mt * 16 + l15) * 120;
        const unsigned short* bbase = QF + ((hh * 2 + nt) * 4) * 512 + ln * 8;
        f32x4 acc = {0.f, 0.f, 0.f, 0.f};
        #pragma unroll
        for (int kk = 0; kk < 4; ++kk)
            acc = MFMA(*(const s16x8*)(arow + kk * 32 + qd * 8),
                       *(const s16x8*)(bbase + kk * 512), acc);
        int nn = nt * 16 + l15;
        if (nn < 20) {
            float bias = qkv_b[hh * 20 + nn];
            #pragma unroll
            for (int reg = 0; reg < 4; ++reg)
                qs[pty * 1536 + (mt * 16 + qd * 4 + reg) * 24 + nn] =
                    f2bf((acc[reg] + bias) * SCALE);
        }
    };

    // ---------------- phase-1 for head 0 (no overlap available yet) ----------------
    for (int e = wv; e < 44; e += 4) {
        if (e < 36) kvjob(e % 12, e / 12, 0, 0);
        else        { int t = e - 36; qjob(t & 3, t >> 2, 0, 0); }
    }
    __syncthreads();

    // ---------------- per-lane constants for the swapped-attention path ----------------
    const int q_l = wv * 16 + l15;               // this wave's q row (0..63)
    const int gq = grp_s[q_l];
    unsigned long long mbits = 0ull;             // bit(t*4+r) = mask(-100) for tok=t*16+qd*4+r
    #pragma unroll
    for (int t = 0; t < 12; ++t)
        #pragma unroll
        for (int r = 0; r < 4; ++r) {
            int tok = t * 16 + qd * 4 + r;
            if (gq != grp_s[tok & 63]) mbits |= (1ull << (t * 4 + r));
        }
    const int srcA = (((qd * 2) & 3) << 4) | l15;
    const int srcB = (((qd * 2 + 1) & 3) << 4) | l15;
    const int msel = qd >> 1;
    const s16x8 zf = {0, 0, 0, 0, 0, 0, 0, 0};

    f32x4 pacc[8];                               // proj accumulators x1^T[c-tile][q=l15]
    #pragma unroll
    for (int i = 0; i < 8; ++i) { f32x4 z = {0.f,0.f,0.f,0.f}; pacc[i] = z; }

    // ---------------- pipelined head loop ----------------
    for (int h = 0; h < 6; ++h) {
        const int pr = h & 1, pw = (h + 1) & 1;

        // ======== EPOCH A: {V(nt2)+Q jobs for h+1} || scores(h) ========
        const float* rbase = RPB + ((size_t)(h * 192 + qd * 4)) * 64 + q_l;
        float vals[48];
        #pragma unroll
        for (int t = 0; t < 12; ++t)
            #pragma unroll
            for (int r = 0; r < 4; ++r)
                vals[t * 4 + r] = rbase[(t * 16 + r) * 64]
                                + (((mbits >> (t * 4 + r)) & 1ull) ? -100.f : 0.f);

        if (h < 5) {
            for (int e = wv; e < 20; e += 4) {
                if (e < 12) kvjob(e, 2, h + 1, pw);
                else        { int t = e - 12; qjob(t & 3, t >> 2, h + 1, pw); }
            }
        }

        s16x8 bQ = zf;
        if (qd < 3) bQ = *(const s16x8*)(qs + pr * 1536 + q_l * 24 + qd * 8);
        f32x4 sc[12];
        #pragma unroll
        for (int t = 0; t < 12; ++t) {
            s16x8 aK = *(const s16x8*)(ks + (t * 16 + l15) * 24 + qd * 8);
            f32x4 z = {0.f, 0.f, 0.f, 0.f};
            sc[t] = MFMA(aK, bQ, z);             // S^T[tok=t*16+qd*4+reg][q=q_l]
        }
        float m = -1e30f;
        #pragma unroll
        for (int t = 0; t < 12; ++t)
            #pragma unroll
            for (int r = 0; r < 4; ++r) {
                float v = vals[t * 4 + r] + sc[t][r];
                vals[t * 4 + r] = v; m = fmaxf(m, v);
            }
        m = fmaxf(m, __shfl_xor(m, 16));
        m = fmaxf(m, __shfl_xor(m, 32));
        __syncthreads();

        // ======== EPOCH B: {K(nt0,nt1) jobs for h+1} || softmax+PV+proj(h) ========
        if (h < 5) {
            for (int e = wv; e < 24; e += 4)
                kvjob(e % 12, (e < 12) ? 0 : 1, h + 1, pw);
        }

        float s = 0.f;
        #pragma unroll
        for (int i = 0; i < 48; ++i) { float ev = __expf(vals[i] - m); vals[i] = ev; s += ev; }
        s += __shfl_xor(s, 16);
        s += __shfl_xor(s, 32);
        float inv = 1.0f / s;

        unsigned int plo[12], phi[12];           // P^T packed
        #pragma unroll
        for (int t = 0; t < 12; ++t) {
            plo[t] = pk2(vals[t * 4 + 0] * inv, vals[t * 4 + 1] * inv);
            phi[t] = pk2(vals[t * 4 + 2] * inv, vals[t * 4 + 3] * inv);
        }

        // PV: O^T = V^T · P^T
        f32x4 o0 = {0.f,0.f,0.f,0.f}, o1 = {0.f,0.f,0.f,0.f};
        #pragma unroll
        for (int kk = 0; kk < 6; ++kk) {
            unsigned int a0 = __shfl(plo[2 * kk],     srcA);
            unsigned int a1 = __shfl(plo[2 * kk + 1], srcA);
            unsigned int b0 = __shfl(phi[2 * kk],     srcA);
            unsigned int b1 = __shfl(phi[2 * kk + 1], srcA);
            unsigned int c0 = __shfl(plo[2 * kk],     srcB);
            unsigned int c1 = __shfl(plo[2 * kk + 1], srcB);
            unsigned int d0 = __shfl(phi[2 * kk],     srcB);
            unsigned int d1 = __shfl(phi[2 * kk + 1], srcB);
            union { s16x8 v; unsigned int u[4]; } bf;
            bf.u[0] = msel ? a1 : a0;
            bf.u[1] = msel ? b1 : b0;
            bf.u[2] = msel ? c1 : c0;
            bf.u[3] = msel ? d1 : d0;
            s16x8 aV0 = *(const s16x8*)(vt + pr * 4000 + l15 * 200 + kk * 32 + qd * 8);
            s16x8 aV1 = zf;
            if (l15 < 4)
                aV1 = *(const s16x8*)(vt + pr * 4000 + (16 + l15) * 200 + kk * 32 + qd * 8);
            o0 = MFMA(aV0, bf.v, o0);            // O^T[d=qd*4+reg][q]
            o1 = MFMA(aV1, bf.v, o1);            // O^T[d=16+qd*4+reg][q]
        }

        // proj: x1^T += PW_h · O^T_h
        {
            unsigned int ol0 = pk2(o0[0], o0[1]), oh0 = pk2(o0[2], o0[3]);
            unsigned int ol1 = pk2(o1[0], o1[1]), oh1 = pk2(o1[2], o1[3]);
            unsigned int w0a = __shfl(ol0, srcA), w0b = __shfl(ol1, srcA);
            unsigned int w1a = __shfl(oh0, srcA), w1b = __shfl(oh1, srcA);
            unsigned int w2a = __shfl(ol0, srcB), w2b = __shfl(ol1, srcB);
            unsigned int w3a = __shfl(oh0, srcB), w3b = __shfl(oh1, srcB);
            union { s16x8 v; unsigned int u[4]; } bo;
            bo.u[0] = msel ? w0b : w0a;
            bo.u[1] = msel ? w1b : w1a;
            bo.u[2] = msel ? w2b : w2a;
            bo.u[3] = msel ? w3b : w3a;
            #pragma unroll
            for (int ct = 0; ct < 8; ++ct) {
                s16x8 aP = *(const s16x8*)(PJF + (h * 8 + ct) * 512 + ln * 8);
                pacc[ct] = MFMA(aP, bo.v, pacc[ct]);
            }
        }
        __syncthreads();
    }

    // ---------------- epilogue: transpose via LDS overlay, blend, scatter ----------------
    float* xo = (float*)smem;                    // [64][129] fp32 overlay on dead xw (33,024 B)
    #pragma unroll
    for (int ct = 0; ct < 8; ++ct)
        #pragma unroll
        for (int r = 0; r < 4; ++r) {
            int c = ct * 16 + qd * 4 + r;
            if (c < 120) xo[q_l * 129 + c] = pacc[ct][r];
        }
    __syncthreads();

    for (int e = tid; e < 64 * 121; e += NT) {
        int r = e / 121, c = e - r * 121;
        int ii = r >> 3, jj = r & 7;
        int y0 = (wh * 8 + ii + 4) & 255;
        int x0 = (ww * 8 + jj + 4) & 255;
        float p = pred_s[r];
        float val;
        if (c < 120)
            val = (p != 0.f) ? (xo[r * 129 + c] + proj_b[c])
                             : quary1[(size_t)widx * 7680 + (size_t)r * 120 + c];
        else
            val = p;
        out[((size_t)(y0 * 256 + x0)) * 121 + c] = val;
    }
}

extern "C" void kernel_launch(void* const* d_in, const int* in_sizes, int n_in,
                              void* d_out, int out_size, void* d_ws, size_t ws_size,
                              hipStream_t stream) {
    const float* x        = (const float*)d_in[0];
    const float* quary0   = (const float*)d_in[1];
    const float* quary1   = (const float*)d_in[2];
    const float* qkv_w    = (const float*)d_in[3];
    const float* qkv_b    = (const float*)d_in[4];
    const float* proj_w   = (const float*)d_in[5];
    const float* proj_b   = (const float*)d_in[6];
    const float* rpb      = (const float*)d_in[7];
    const float* pm_w     = (const float*)d_in[8];
    const float* pm_b     = (const float*)d_in[9];
    const int*   rel_idx  = (const int*)d_in[11];
    float* out = (float*)d_out;
    unsigned char* wsb = (unsigned char*)d_ws;

    prep<<<128, 512, 0, stream>>>(qkv_w, proj_w, rpb, rel_idx, wsb);
    swin_mfma<<<1024, NT, 0, stream>>>(x, quary0, quary1, qkv_b, proj_b,
                                       pm_w, pm_b, wsb, out);
}